// Round 1
// baseline (1041.814 us; speedup 1.0000x reference)
//
#include <hip/hip_runtime.h>
#include <stdint.h>

// Problem constants (fixed by the reference)
#define M_TOT 16384   // B*S
#define K_TOT 4864    // IN_DIM
#define N_TOT 640     // G*V
#define GRP   2
#define NV    320
#define CVD   128     // CV_DIM / G

// MFMA GEMM tile
#define BM 128
#define BN 320        // one full group per block (bx = group)
#define BK 32
#define KITERS (K_TOT / BK)   // 152

#define MARGIN 2.0e-3f   // 2*eps; approx-logit |err| measured-model ~3e-5 max

typedef __attribute__((ext_vector_type(8))) short short8;
typedef __attribute__((ext_vector_type(4))) float f32x4;

// ---- ws layout (bytes) ----
#define WS_FLAGCNT  0
#define WS_COUNTS   256                      // 640 u32
#define WS_FLAGLIST 4096                     // 65536 u32 (cap > worst case 32768)
#define WS_PACKED   (4096 + 262144)          // 16384*2 u64
#define WS_WT       (1u << 20)               // W_hi_t then W_lo_t, each 640*4864 u16

__device__ __forceinline__ unsigned int mono_u32(float f) {
    unsigned int b = __float_as_uint(f);
    return b ^ ((unsigned int)((int)b >> 31) | 0x80000000u);  // order-preserving
}
__device__ __forceinline__ unsigned short f2bf(float x) {   // RNE, finite inputs
    unsigned int u = __float_as_uint(x);
    return (unsigned short)((u + 0x7fffu + ((u >> 16) & 1u)) >> 16);
}
__device__ __forceinline__ float bf2f(unsigned short h) {
    return __uint_as_float(((unsigned int)h) << 16);
}
__device__ __forceinline__ void gld16(const void* g, void* l) {
    __builtin_amdgcn_global_load_lds(
        (const __attribute__((address_space(1))) unsigned int*)g,
        (__attribute__((address_space(3))) unsigned int*)l, 16, 0, 0);
}

// ---------------- W -> W_hi_t / W_lo_t (bf16, transposed to [n][k]) -------------
__global__ __launch_bounds__(256)
void convert_wt(const float* __restrict__ W, unsigned short* __restrict__ wt)
{
    __shared__ float sW[64][68];
    const int k0 = blockIdx.x * 64;          // 76 tiles
    const int n0 = blockIdx.y * 64;          // 10 tiles
    const int tid = threadIdx.x;
    for (int l = tid; l < 64 * 16; l += 256) {
        int kr = l >> 4, nc = (l & 15) * 4;
        float4 v = *(const float4*)(W + (size_t)(k0 + kr) * N_TOT + n0 + nc);
        sW[kr][nc] = v.x; sW[kr][nc + 1] = v.y; sW[kr][nc + 2] = v.z; sW[kr][nc + 3] = v.w;
    }
    __syncthreads();
    unsigned short* whi = wt;
    unsigned short* wlo = wt + (size_t)N_TOT * K_TOT;
    for (int l = tid; l < 64 * 8; l += 256) {
        int nr = l >> 3, ko = (l & 7) * 8;
        union { short8 v; unsigned short u[8]; } hu, lu;
#pragma unroll
        for (int j = 0; j < 8; ++j) {
            float x = sW[ko + j][nr];
            unsigned short hb = f2bf(x);
            hu.u[j] = hb;
            lu.u[j] = f2bf(x - bf2f(hb));
        }
        size_t off = (size_t)(n0 + nr) * K_TOT + k0 + ko;   // 16B aligned
        *(short8*)(whi + off) = hu.v;
        *(short8*)(wlo + off) = lu.v;
    }
}

// ---------------- MFMA GEMM + argmax(+margin flag) ------------------------------
// LDS layout: row of 64 shorts = 8 slots of 16B; slot(stream,oct,row) =
// (stream*4 + oct) ^ (row&7)  -> 2-way-max bank aliasing on b128 reads.
__device__ __forceinline__ void stage_b(const unsigned short* __restrict__ wt,
                                        short* sBbuf, int bx, int kk, int tid)
{
#pragma unroll
    for (int r = 0; r < 10; ++r) {
        int c = r * 256 + tid;                  // 2560 chunks = [row][slot]
        int row = c >> 3, slot = c & 7;
        int sv = slot ^ (row & 7);
        int half = sv >> 2, oct = sv & 3;       // which stream / which k-oct
        const unsigned short* gp = wt + (size_t)half * N_TOT * K_TOT
            + (size_t)(bx * NV + row) * K_TOT + kk + (oct << 3);
        gld16(gp, sBbuf + (size_t)c * 8);       // lane-linear LDS dest
    }
}

__global__ __launch_bounds__(256, 1)
void gemm_mfma(const float* __restrict__ A, const unsigned short* __restrict__ wt,
               const float* __restrict__ bias,
               unsigned long long* __restrict__ packed,
               unsigned int* __restrict__ flagcnt, unsigned int* __restrict__ flaglist)
{
    __shared__ short sA[2][BM][64];      // [buf][row][slot*8] 32 KB
    __shared__ short sB[2][BN][64];      // [buf][row][slot*8] 80 KB
    __shared__ uint4 sRed[BM][4];        // cross-wave argmax merge, 8 KB

    const int tid  = threadIdx.x;
    const int L    = tid & 63;
    const int w    = tid >> 6;        // 0..3 : wave = wcol, cols w*80..
    const int quad = L >> 4;
    const int lrow = L & 15;
    const int bx   = blockIdx.x;      // group 0/1
    const int m0   = blockIdx.y * BM;

    // read-side LDS slots (row&7 == lrow&7 for all frag rows)
    const int sh = (quad ^ (lrow & 7)) << 3;          // hi stream, oct=quad
    const int sl = ((4 | quad) ^ (lrow & 7)) << 3;    // lo stream, oct=quad

    // A staging mapping: thread -> (arow 0..127, k-half 0/1), 16 f32 each
    const int arow = tid >> 1;
    const int apar = tid & 1;
    const float* Ap = A + (size_t)(m0 + arow) * K_TOT + apar * 16;
    const int o0 = 2 * apar, o1 = 2 * apar + 1;
    const int sH0 = (o0 ^ (arow & 7)) << 3;
    const int sH1 = (o1 ^ (arow & 7)) << 3;
    const int sL0 = ((4 | o0) ^ (arow & 7)) << 3;
    const int sL1 = ((4 | o1) ^ (arow & 7)) << 3;

    f32x4 acc[8][5];
#pragma unroll
    for (int i = 0; i < 8; ++i)
#pragma unroll
        for (int j = 0; j < 5; ++j) acc[i][j] = (f32x4){0.f, 0.f, 0.f, 0.f};

    // ---- prologue: stage tile 0 into buf 0
    {
        stage_b(wt, &sB[0][0][0], bx, 0, tid);
        float4 a0 = *(const float4*)(Ap);
        float4 a1 = *(const float4*)(Ap + 4);
        float4 a2 = *(const float4*)(Ap + 8);
        float4 a3 = *(const float4*)(Ap + 12);
        union { short8 v; unsigned short u[8]; } h0, l0, h1, l1;
        float xs0[8] = {a0.x, a0.y, a0.z, a0.w, a1.x, a1.y, a1.z, a1.w};
        float xs1[8] = {a2.x, a2.y, a2.z, a2.w, a3.x, a3.y, a3.z, a3.w};
#pragma unroll
        for (int j = 0; j < 8; ++j) {
            unsigned short hb = f2bf(xs0[j]);
            h0.u[j] = hb; l0.u[j] = f2bf(xs0[j] - bf2f(hb));
            unsigned short hc = f2bf(xs1[j]);
            h1.u[j] = hc; l1.u[j] = f2bf(xs1[j] - bf2f(hc));
        }
        *(short8*)&sA[0][arow][sH0] = h0.v;
        *(short8*)&sA[0][arow][sH1] = h1.v;
        *(short8*)&sA[0][arow][sL0] = l0.v;
        *(short8*)&sA[0][arow][sL1] = l1.v;
    }
    __syncthreads();

    int k0 = 0;
    for (int it = 0; it < KITERS; ++it) {
        const int buf = it & 1;
        const int kn  = k0 + BK;
        float4 a0, a1, a2, a3;
        const bool more = (it + 1 < KITERS);
        if (more) {
            stage_b(wt, &sB[buf ^ 1][0][0], bx, kn, tid);   // async into other buf
            a0 = *(const float4*)(Ap + kn);                 // A prefetch (regs)
            a1 = *(const float4*)(Ap + kn + 4);
            a2 = *(const float4*)(Ap + kn + 8);
            a3 = *(const float4*)(Ap + kn + 12);
        }
        // ---- MFMA on buf
        short8 ah[8], al[8];
#pragma unroll
        for (int fi = 0; fi < 8; ++fi) {
            int mloc = fi * 16 + lrow;
            ah[fi] = *(const short8*)&sA[buf][mloc][sh];
            al[fi] = *(const short8*)&sA[buf][mloc][sl];
        }
#pragma unroll
        for (int fj = 0; fj < 5; ++fj) {
            int nloc = w * 80 + fj * 16 + lrow;
            short8 bh = *(const short8*)&sB[buf][nloc][sh];
            short8 bl = *(const short8*)&sB[buf][nloc][sl];
#pragma unroll
            for (int fi = 0; fi < 8; ++fi) {
                acc[fi][fj] = __builtin_amdgcn_mfma_f32_16x16x32_bf16(ah[fi], bh, acc[fi][fj], 0, 0, 0);
                acc[fi][fj] = __builtin_amdgcn_mfma_f32_16x16x32_bf16(ah[fi], bl, acc[fi][fj], 0, 0, 0);
                acc[fi][fj] = __builtin_amdgcn_mfma_f32_16x16x32_bf16(al[fi], bh, acc[fi][fj], 0, 0, 0);
            }
        }
        if (more) {
            union { short8 v; unsigned short u[8]; } h0, l0, h1, l1;
            float xs0[8] = {a0.x, a0.y, a0.z, a0.w, a1.x, a1.y, a1.z, a1.w};
            float xs1[8] = {a2.x, a2.y, a2.z, a2.w, a3.x, a3.y, a3.z, a3.w};
#pragma unroll
            for (int j = 0; j < 8; ++j) {
                unsigned short hb = f2bf(xs0[j]);
                h0.u[j] = hb; l0.u[j] = f2bf(xs0[j] - bf2f(hb));
                unsigned short hc = f2bf(xs1[j]);
                h1.u[j] = hc; l1.u[j] = f2bf(xs1[j] - bf2f(hc));
            }
            *(short8*)&sA[buf ^ 1][arow][sH0] = h0.v;
            *(short8*)&sA[buf ^ 1][arow][sH1] = h1.v;
            *(short8*)&sA[buf ^ 1][arow][sL0] = l0.v;
            *(short8*)&sA[buf ^ 1][arow][sL1] = l1.v;
        }
        __syncthreads();   // waits gld (issued ~full iter ago) + ds_writes
        k0 = kn;
    }

    // ---- epilogue: per-row top1(packed) + top2 value over this wave's 80 cols
    float bs[5];
#pragma unroll
    for (int fj = 0; fj < 5; ++fj)
        bs[fj] = bias[bx * NV + w * 80 + fj * 16 + lrow];

#pragma unroll
    for (int fi = 0; fi < 8; ++fi) {
#pragma unroll
        for (int r = 0; r < 4; ++r) {
            unsigned long long pv = 0; float v1 = 0.f, v2 = -3.4e38f;
#pragma unroll
            for (int fj = 0; fj < 5; ++fj) {
                float v = acc[fi][fj][r] + bs[fj];
                int cig = w * 80 + fj * 16 + lrow;            // col in group
                unsigned long long p = ((unsigned long long)mono_u32(v) << 32)
                                     | (unsigned int)(NV - 1 - cig);
                if (fj == 0) { pv = p; v1 = v; }
                else if (p > pv) { v2 = v1; v1 = v; pv = p; }
                else { v2 = fmaxf(v2, v); }
            }
#pragma unroll
            for (int msk = 1; msk < 16; msk <<= 1) {          // 16 lanes share a row
                unsigned long long opv = __shfl_xor(pv, msk);
                float ov1 = __shfl_xor(v1, msk);
                float ov2 = __shfl_xor(v2, msk);
                if (opv > pv) { v2 = fmaxf(v1, ov2); v1 = ov1; pv = opv; }
                else          { v2 = fmaxf(v2, ov1); }
            }
            if (lrow == 0) {
                int row_blk = fi * 16 + quad * 4 + r;
                uint4 e;
                e.x = (unsigned int)(pv & 0xFFFFFFFFull);
                e.y = (unsigned int)(pv >> 32);
                e.z = __float_as_uint(v2);
                e.w = __float_as_uint(v1);
                sRed[row_blk][w] = e;
            }
        }
    }
    __syncthreads();

    if (tid < BM) {   // final 4-way merge per row, store + flag
        unsigned long long pv = 0; float v1 = -3.4e38f, v2 = -3.4e38f;
#pragma unroll
        for (int wc = 0; wc < 4; ++wc) {
            uint4 e = sRed[tid][wc];
            unsigned long long opv = ((unsigned long long)e.y << 32) | e.x;
            float ov1 = __uint_as_float(e.w), ov2 = __uint_as_float(e.z);
            if (opv > pv) { v2 = fmaxf(v1, ov2); v1 = ov1; pv = opv; }
            else          { v2 = fmaxf(v2, ov1); }
        }
        packed[(size_t)(m0 + tid) * GRP + bx] = pv;           // block-exclusive
        if (v1 - v2 <= MARGIN) {
            unsigned int slot = atomicAdd(flagcnt, 1u);
            flaglist[slot] = ((unsigned int)(m0 + tid) << 1) | (unsigned int)bx;
        }
    }
}

// ---------------- exact fp32 recheck of flagged (row, group) --------------------
// Processes up to 4 items per W-stream (per-item arithmetic identical to the
// previous single-item version: same kseg split, same fmaf order).
#define RCH_IPB 4
__global__ __launch_bounds__(320)
void recheck(const float* __restrict__ A, const float* __restrict__ W,
             const float* __restrict__ bias,
             const unsigned int* __restrict__ flagcnt,
             const unsigned int* __restrict__ flaglist,
             unsigned long long* __restrict__ packed)
{
    __shared__ float  sAr[RCH_IPB][K_TOT];     // 77824 B
    __shared__ float4 sPart[RCH_IPB][320];     // 20480 B
    __shared__ float  sVals[RCH_IPB][NV];      // 5120 B
    __shared__ int    sRow[RCH_IPB], sG[RCH_IPB];
    const int tid = threadIdx.x;
    const unsigned int cnt = *flagcnt;
    const int kseg = tid / 80, c4 = tid % 80;   // 4 k-segments x 80 col-quads
    for (unsigned int base = (unsigned int)blockIdx.x * RCH_IPB; base < cnt;
         base += (unsigned int)gridDim.x * RCH_IPB) {
        const unsigned int nit = (cnt - base < (unsigned int)RCH_IPB)
                               ? (cnt - base) : (unsigned int)RCH_IPB;
        __syncthreads();
        if (tid < RCH_IPB) {
            unsigned int src = base + (unsigned int)tid;
            if (src >= cnt) src = base;          // clamp: duplicate item 0 (not stored)
            unsigned int item = flaglist[src];
            sRow[tid] = (int)(item >> 1);
            sG[tid]   = (int)(item & 1);
        }
        __syncthreads();
        for (int l = tid; l < RCH_IPB * (K_TOT / 4); l += 320) {
            int j = l / (K_TOT / 4), off = l - j * (K_TOT / 4);
            *(float4*)&sAr[j][off * 4] =
                *(const float4*)(A + (size_t)sRow[j] * K_TOT + off * 4);
        }
        __syncthreads();
        float4 ac0 = {0.f,0.f,0.f,0.f}, ac1 = {0.f,0.f,0.f,0.f};
        float4 ac2 = {0.f,0.f,0.f,0.f}, ac3 = {0.f,0.f,0.f,0.f};
        const float* wbase = W + (size_t)(kseg * 1216) * N_TOT + c4 * 4;
        const float* w0 = wbase + sG[0] * NV;
        const float* w1 = wbase + sG[1] * NV;
        const float* w2 = wbase + sG[2] * NV;
        const float* w3 = wbase + sG[3] * NV;
        const float* a0p = &sAr[0][kseg * 1216];
        const float* a1p = &sAr[1][kseg * 1216];
        const float* a2p = &sAr[2][kseg * 1216];
        const float* a3p = &sAr[3][kseg * 1216];
        for (int k = 0; k < 1216; ++k) {
            size_t ro = (size_t)k * N_TOT;
            float4 wv0 = *(const float4*)(w0 + ro); float av0 = a0p[k];
            ac0.x = fmaf(av0, wv0.x, ac0.x); ac0.y = fmaf(av0, wv0.y, ac0.y);
            ac0.z = fmaf(av0, wv0.z, ac0.z); ac0.w = fmaf(av0, wv0.w, ac0.w);
            float4 wv1 = *(const float4*)(w1 + ro); float av1 = a1p[k];
            ac1.x = fmaf(av1, wv1.x, ac1.x); ac1.y = fmaf(av1, wv1.y, ac1.y);
            ac1.z = fmaf(av1, wv1.z, ac1.z); ac1.w = fmaf(av1, wv1.w, ac1.w);
            float4 wv2 = *(const float4*)(w2 + ro); float av2 = a2p[k];
            ac2.x = fmaf(av2, wv2.x, ac2.x); ac2.y = fmaf(av2, wv2.y, ac2.y);
            ac2.z = fmaf(av2, wv2.z, ac2.z); ac2.w = fmaf(av2, wv2.w, ac2.w);
            float4 wv3 = *(const float4*)(w3 + ro); float av3 = a3p[k];
            ac3.x = fmaf(av3, wv3.x, ac3.x); ac3.y = fmaf(av3, wv3.y, ac3.y);
            ac3.z = fmaf(av3, wv3.z, ac3.z); ac3.w = fmaf(av3, wv3.w, ac3.w);
        }
        sPart[0][tid] = ac0; sPart[1][tid] = ac1;
        sPart[2][tid] = ac2; sPart[3][tid] = ac3;
        __syncthreads();
        if (tid < 80) {
#pragma unroll
            for (int j = 0; j < RCH_IPB; ++j) {
                float4 s = {0.f, 0.f, 0.f, 0.f};
#pragma unroll
                for (int ks = 0; ks < 4; ++ks) {          // fixed order: deterministic
                    float4 p = sPart[j][ks * 80 + tid];
                    s.x += p.x; s.y += p.y; s.z += p.z; s.w += p.w;
                }
                float4 bb = *(const float4*)(bias + sG[j] * NV + tid * 4);
                sVals[j][tid * 4 + 0] = s.x + bb.x;
                sVals[j][tid * 4 + 1] = s.y + bb.y;
                sVals[j][tid * 4 + 2] = s.z + bb.z;
                sVals[j][tid * 4 + 3] = s.w + bb.w;
            }
        }
        __syncthreads();
        if (tid < (int)nit) {
            float best = sVals[tid][0]; int bi = 0;
            for (int c = 1; c < NV; ++c)
                if (sVals[tid][c] > best) { best = sVals[tid][c]; bi = c; }  // first max wins
            packed[(size_t)sRow[tid] * GRP + sG[tid]] =
                ((unsigned long long)mono_u32(best) << 32) | (unsigned int)(NV - 1 - bi);
        }
    }
}

// ---------------- gather + histogram, perplexity --------------------------------
__global__ __launch_bounds__(256)
void gather_hist(const unsigned long long* __restrict__ packed,
                 const float* __restrict__ cv,
                 float* __restrict__ out, int* __restrict__ counts)
{
    const int m = blockIdx.x;
    const int t = threadIdx.x;
    const int g = t >> 7;
    const unsigned long long p = packed[(size_t)m * GRP + g];
    const int idx = (NV - 1) - (int)(p & 0xFFFFFFFFull);
    const int c = t & 127;
    out[(size_t)m * (GRP * CVD) + t] = cv[((size_t)g * NV + idx) * CVD + c];
    if (c == 0) atomicAdd(&counts[g * NV + idx], 1);
}

__global__ void perplexity_k(const int* __restrict__ counts, float* __restrict__ outp)
{
    __shared__ float sred[GRP * NV];
    const int t = threadIdx.x;        // 640
    const float marg = (float)counts[t] * (1.0f / (float)M_TOT);
    sred[t] = marg * logf(marg + 1e-7f);
    __syncthreads();
    if (t < GRP) {
        float s = 0.f;
        for (int i = 0; i < NV; ++i) s += sred[t * NV + i];
        sred[t] = expf(-s);
    }
    __syncthreads();
    if (t == 0) outp[0] = sred[0] + sred[1];
}

extern "C" void kernel_launch(void* const* d_in, const int* in_sizes, int n_in,
                              void* d_out, int out_size, void* d_ws, size_t ws_size,
                              hipStream_t stream)
{
    const float* A    = (const float*)d_in[0];   // (16,1024,4864) f32
    const float* Wm   = (const float*)d_in[1];   // (4864,640) f32
    const float* bias = (const float*)d_in[2];   // (640,) f32
    const float* cv   = (const float*)d_in[3];   // (1,640,128) f32

    float* out = (float*)d_out;                       // (16,1024,256)
    float* ppl = out + (size_t)M_TOT * (GRP * CVD);   // +1 scalar

    char* ws = (char*)d_ws;
    unsigned int*       flagcnt  = (unsigned int*)(ws + WS_FLAGCNT);
    int*                counts   = (int*)(ws + WS_COUNTS);
    unsigned int*       flaglist = (unsigned int*)(ws + WS_FLAGLIST);
    unsigned long long* packed   = (unsigned long long*)(ws + WS_PACKED);
    unsigned short*     wt       = (unsigned short*)(ws + WS_WT);

    hipMemsetAsync(d_ws, 0, 4096, stream);            // flagcnt + counts
    convert_wt<<<dim3(76, 10), 256, 0, stream>>>(Wm, wt);
    gemm_mfma<<<dim3(2, 128), 256, 0, stream>>>(A, wt, bias, packed, flagcnt, flaglist);
    recheck<<<256, 320, 0, stream>>>(A, Wm, bias, flagcnt, flaglist, packed);
    gather_hist<<<M_TOT, 256, 0, stream>>>(packed, cv, out, counts);
    perplexity_k<<<1, GRP * NV, 0, stream>>>(counts, ppl);
}

// Round 2
// 881.063 us; speedup vs baseline: 1.1825x; 1.1825x over previous
//
#include <hip/hip_runtime.h>
#include <stdint.h>

// Problem constants (fixed by the reference)
#define M_TOT 16384   // B*S
#define K_TOT 4864    // IN_DIM
#define N_TOT 640     // G*V
#define GRP   2
#define NV    320
#define CVD   128     // CV_DIM / G

// MFMA GEMM tile
#define BM 128
#define BN 320        // one full group per block (bx = group)
#define BK 32
#define KITERS (K_TOT / BK)   // 152

#define MARGIN 5.0e-4f   // approx-logit |err| measured ~3e-5 max; 8x above 2*err

typedef __attribute__((ext_vector_type(8))) short short8;
typedef __attribute__((ext_vector_type(4))) float f32x4;

// ---- ws layout (bytes) ----
#define WS_FLAGCNT  0                        // 2 u32 (one per group)
#define WS_COUNTS   256                      // 640 u32
#define WS_FLAGLIST 4096                     // 2 * 32768 u32 (per-group lists)
#define FLAGCAP     32768
#define WS_PACKED   (4096 + 262144)          // 16384*2 u64
#define WS_WT       (1u << 20)               // W_hi_t then W_lo_t, each 640*4864 u16

__device__ __forceinline__ unsigned int mono_u32(float f) {
    unsigned int b = __float_as_uint(f);
    return b ^ ((unsigned int)((int)b >> 31) | 0x80000000u);  // order-preserving
}
__device__ __forceinline__ unsigned short f2bf(float x) {   // RNE, finite inputs
    unsigned int u = __float_as_uint(x);
    return (unsigned short)((u + 0x7fffu + ((u >> 16) & 1u)) >> 16);
}
__device__ __forceinline__ float bf2f(unsigned short h) {
    return __uint_as_float(((unsigned int)h) << 16);
}
__device__ __forceinline__ void gld16(const void* g, void* l) {
    __builtin_amdgcn_global_load_lds(
        (const __attribute__((address_space(1))) unsigned int*)g,
        (__attribute__((address_space(3))) unsigned int*)l, 16, 0, 0);
}

// ---------------- W -> W_hi_t / W_lo_t (bf16, transposed to [n][k]) -------------
__global__ __launch_bounds__(256)
void convert_wt(const float* __restrict__ W, unsigned short* __restrict__ wt)
{
    __shared__ float sW[64][68];
    const int k0 = blockIdx.x * 64;          // 76 tiles
    const int n0 = blockIdx.y * 64;          // 10 tiles
    const int tid = threadIdx.x;
    for (int l = tid; l < 64 * 16; l += 256) {
        int kr = l >> 4, nc = (l & 15) * 4;
        float4 v = *(const float4*)(W + (size_t)(k0 + kr) * N_TOT + n0 + nc);
        sW[kr][nc] = v.x; sW[kr][nc + 1] = v.y; sW[kr][nc + 2] = v.z; sW[kr][nc + 3] = v.w;
    }
    __syncthreads();
    unsigned short* whi = wt;
    unsigned short* wlo = wt + (size_t)N_TOT * K_TOT;
    for (int l = tid; l < 64 * 8; l += 256) {
        int nr = l >> 3, ko = (l & 7) * 8;
        union { short8 v; unsigned short u[8]; } hu, lu;
#pragma unroll
        for (int j = 0; j < 8; ++j) {
            float x = sW[ko + j][nr];
            unsigned short hb = f2bf(x);
            hu.u[j] = hb;
            lu.u[j] = f2bf(x - bf2f(hb));
        }
        size_t off = (size_t)(n0 + nr) * K_TOT + k0 + ko;   // 16B aligned
        *(short8*)(whi + off) = hu.v;
        *(short8*)(wlo + off) = lu.v;
    }
}

// ---------------- MFMA GEMM + argmax(+margin flag) ------------------------------
// LDS layout: row of 64 shorts = 8 slots of 16B; slot(stream,oct,row) =
// (stream*4 + oct) ^ (row&7)  -> low bank aliasing on b128 reads (measured 5e6).
__device__ __forceinline__ void stage_b(const unsigned short* __restrict__ wt,
                                        short* sBbuf, int bx, int kk, int tid)
{
#pragma unroll
    for (int r = 0; r < 5; ++r) {
        int c = r * 512 + tid;                  // 2560 chunks = [row][slot]
        int row = c >> 3, slot = c & 7;
        int sv = slot ^ (row & 7);
        int half = sv >> 2, oct = sv & 3;       // which stream / which k-oct
        const unsigned short* gp = wt + (size_t)half * N_TOT * K_TOT
            + (size_t)(bx * NV + row) * K_TOT + kk + (oct << 3);
        gld16(gp, sBbuf + (size_t)c * 8);       // lane-linear LDS dest
    }
}

__global__ __launch_bounds__(512, 2)
void gemm_mfma(const float* __restrict__ A, const unsigned short* __restrict__ wt,
               const float* __restrict__ bias,
               unsigned long long* __restrict__ packed,
               unsigned int* __restrict__ flagcnt, unsigned int* __restrict__ flaglist)
{
    __shared__ short sA[2][BM][64];      // [buf][row][slot*8] 32 KB
    __shared__ short sB[2][BN][64];      // [buf][row][slot*8] 80 KB
    __shared__ uint4 sRed[BM][4];        // cross-wave argmax merge, 8 KB

    const int tid  = threadIdx.x;
    const int L    = tid & 63;
    const int w    = tid >> 6;        // 0..7
    const int quad = L >> 4;
    const int lrow = L & 15;
    const int wrow = w >> 2;          // 0..1 : rows wrow*64..
    const int wcol = w & 3;           // 0..3 : cols wcol*80..
    const int bx   = blockIdx.x;      // group 0/1
    const int m0   = blockIdx.y * BM;

    // read-side LDS slots (row&7 == lrow&7 for all frag rows)
    const int sh = (quad ^ (lrow & 7)) << 3;          // hi stream, oct=quad
    const int sl = ((4 | quad) ^ (lrow & 7)) << 3;    // lo stream, oct=quad

    // A staging mapping: thread -> (arow 0..127, aoct 0..3), 8 f32 each
    const int arow = tid >> 2;
    const int aoct = tid & 3;
    const float* Ap = A + (size_t)(m0 + arow) * K_TOT + aoct * 8;
    const int sHa = (aoct ^ (arow & 7)) << 3;
    const int sLa = ((4 | aoct) ^ (arow & 7)) << 3;

    f32x4 acc[4][5];
#pragma unroll
    for (int i = 0; i < 4; ++i)
#pragma unroll
        for (int j = 0; j < 5; ++j) acc[i][j] = (f32x4){0.f, 0.f, 0.f, 0.f};

    // ---- prologue: stage tile 0 into buf 0 (A loads issued before glds)
    {
        float4 a0 = *(const float4*)(Ap);
        float4 a1 = *(const float4*)(Ap + 4);
        stage_b(wt, &sB[0][0][0], bx, 0, tid);
        union { short8 v; unsigned short u[8]; } hu, lu;
        float xs[8] = {a0.x, a0.y, a0.z, a0.w, a1.x, a1.y, a1.z, a1.w};
#pragma unroll
        for (int j = 0; j < 8; ++j) {
            unsigned short hb = f2bf(xs[j]);
            hu.u[j] = hb; lu.u[j] = f2bf(xs[j] - bf2f(hb));
        }
        *(short8*)&sA[0][arow][sHa] = hu.v;
        *(short8*)&sA[0][arow][sLa] = lu.v;
    }
    __syncthreads();

    int k0 = 0;
    for (int it = 0; it < KITERS; ++it) {
        const int buf = it & 1;
        const int kn  = k0 + BK;
        float4 a0, a1;
        const bool more = (it + 1 < KITERS);
        if (more) {
            a0 = *(const float4*)(Ap + kn);                 // A loads FIRST (oldest
            a1 = *(const float4*)(Ap + kn + 4);             //  in vmcnt FIFO)
            stage_b(wt, &sB[buf ^ 1][0][0], bx, kn, tid);   // then async glds
        }
        // ---- MFMA on buf
        short8 ah[4], al[4];
#pragma unroll
        for (int fi = 0; fi < 4; ++fi) {
            int mloc = wrow * 64 + fi * 16 + lrow;
            ah[fi] = *(const short8*)&sA[buf][mloc][sh];
            al[fi] = *(const short8*)&sA[buf][mloc][sl];
        }
#pragma unroll
        for (int fj = 0; fj < 5; ++fj) {
            int nloc = wcol * 80 + fj * 16 + lrow;
            short8 bh = *(const short8*)&sB[buf][nloc][sh];
            short8 bl = *(const short8*)&sB[buf][nloc][sl];
#pragma unroll
            for (int fi = 0; fi < 4; ++fi) {
                acc[fi][fj] = __builtin_amdgcn_mfma_f32_16x16x32_bf16(ah[fi], bh, acc[fi][fj], 0, 0, 0);
                acc[fi][fj] = __builtin_amdgcn_mfma_f32_16x16x32_bf16(ah[fi], bl, acc[fi][fj], 0, 0, 0);
                acc[fi][fj] = __builtin_amdgcn_mfma_f32_16x16x32_bf16(al[fi], bh, acc[fi][fj], 0, 0, 0);
            }
        }
        if (more) {   // convert waits only the A loads (vmcnt leaves glds in flight)
            union { short8 v; unsigned short u[8]; } hu, lu;
            float xs[8] = {a0.x, a0.y, a0.z, a0.w, a1.x, a1.y, a1.z, a1.w};
#pragma unroll
            for (int j = 0; j < 8; ++j) {
                unsigned short hb = f2bf(xs[j]);
                hu.u[j] = hb; lu.u[j] = f2bf(xs[j] - bf2f(hb));
            }
            *(short8*)&sA[buf ^ 1][arow][sHa] = hu.v;
            *(short8*)&sA[buf ^ 1][arow][sLa] = lu.v;
        }
        __syncthreads();   // drains glds (issued ~full iter ago: cheap)
        k0 = kn;
    }

    // ---- epilogue: per-row top1(packed) + top2 value over this wave's 80 cols
    float bs[5];
#pragma unroll
    for (int fj = 0; fj < 5; ++fj)
        bs[fj] = bias[bx * NV + wcol * 80 + fj * 16 + lrow];

#pragma unroll
    for (int fi = 0; fi < 4; ++fi) {
#pragma unroll
        for (int r = 0; r < 4; ++r) {
            unsigned long long pv = 0; float v1 = 0.f, v2 = -3.4e38f;
#pragma unroll
            for (int fj = 0; fj < 5; ++fj) {
                float v = acc[fi][fj][r] + bs[fj];
                int cig = wcol * 80 + fj * 16 + lrow;         // col in group
                unsigned long long p = ((unsigned long long)mono_u32(v) << 32)
                                     | (unsigned int)(NV - 1 - cig);
                if (fj == 0) { pv = p; v1 = v; }
                else if (p > pv) { v2 = v1; v1 = v; pv = p; }
                else { v2 = fmaxf(v2, v); }
            }
#pragma unroll
            for (int msk = 1; msk < 16; msk <<= 1) {          // 16 lanes share a row
                unsigned long long opv = __shfl_xor(pv, msk);
                float ov1 = __shfl_xor(v1, msk);
                float ov2 = __shfl_xor(v2, msk);
                if (opv > pv) { v2 = fmaxf(v1, ov2); v1 = ov1; pv = opv; }
                else          { v2 = fmaxf(v2, ov1); }
            }
            if (lrow == 0) {
                int row_blk = wrow * 64 + fi * 16 + quad * 4 + r;
                uint4 e;
                e.x = (unsigned int)(pv & 0xFFFFFFFFull);
                e.y = (unsigned int)(pv >> 32);
                e.z = __float_as_uint(v2);
                e.w = __float_as_uint(v1);
                sRed[row_blk][wcol] = e;
            }
        }
    }
    __syncthreads();

    if (tid < BM) {   // final 4-way merge per row, store + flag
        unsigned long long pv = 0; float v1 = -3.4e38f, v2 = -3.4e38f;
#pragma unroll
        for (int wc = 0; wc < 4; ++wc) {
            uint4 e = sRed[tid][wc];
            unsigned long long opv = ((unsigned long long)e.y << 32) | e.x;
            float ov1 = __uint_as_float(e.w), ov2 = __uint_as_float(e.z);
            if (opv > pv) { v2 = fmaxf(v1, ov2); v1 = ov1; pv = opv; }
            else          { v2 = fmaxf(v2, ov1); }
        }
        packed[(size_t)(m0 + tid) * GRP + bx] = pv;           // block-exclusive
        if (v1 - v2 <= MARGIN) {
            unsigned int slot = atomicAdd(&flagcnt[bx], 1u);  // per-group list
            flaglist[bx * FLAGCAP + slot] = (unsigned int)(m0 + tid);
        }
    }
}

// ---------------- exact fp32 recheck of flagged (row, group) --------------------
// 4 same-group rows per W-stream: one float4 W load feeds 4 FMA chains.
// Per-item arithmetic identical to the single-item version (same kseg split,
// same fmaf order, same fixed-order 4-way reduce).
#define RCH_IPB 4
__global__ __launch_bounds__(320)
void recheck(const float* __restrict__ A, const float* __restrict__ W,
             const float* __restrict__ bias,
             const unsigned int* __restrict__ flagcnt,
             const unsigned int* __restrict__ flaglist,
             unsigned long long* __restrict__ packed)
{
    __shared__ float  sAr[RCH_IPB][K_TOT];     // 77824 B
    __shared__ float4 sPart[RCH_IPB][320];     // 20480 B
    __shared__ float  sVals[RCH_IPB][NV];      // 5120 B
    __shared__ int    sRow[RCH_IPB];
    const int tid = threadIdx.x;
    const int g   = blockIdx.x & 1;                 // block's group (uniform items)
    const unsigned int cnt = flagcnt[g];
    const unsigned int* list = flaglist + g * FLAGCAP;
    const int kseg = tid / 80, c4 = tid % 80;   // 4 k-segments x 80 col-quads
    for (unsigned int base = (unsigned int)(blockIdx.x >> 1) * RCH_IPB; base < cnt;
         base += (unsigned int)(gridDim.x >> 1) * RCH_IPB) {
        const unsigned int nit = (cnt - base < (unsigned int)RCH_IPB)
                               ? (cnt - base) : (unsigned int)RCH_IPB;
        __syncthreads();
        if (tid < RCH_IPB) {
            unsigned int src = base + (unsigned int)tid;
            if (src >= cnt) src = base;          // clamp: duplicate item 0 (not stored)
            sRow[tid] = (int)list[src];
        }
        __syncthreads();
        for (int l = tid; l < RCH_IPB * (K_TOT / 4); l += 320) {
            int j = l / (K_TOT / 4), off = l - j * (K_TOT / 4);
            *(float4*)&sAr[j][off * 4] =
                *(const float4*)(A + (size_t)sRow[j] * K_TOT + off * 4);
        }
        __syncthreads();
        float4 ac0 = {0.f,0.f,0.f,0.f}, ac1 = {0.f,0.f,0.f,0.f};
        float4 ac2 = {0.f,0.f,0.f,0.f}, ac3 = {0.f,0.f,0.f,0.f};
        const float* wp = W + (size_t)(kseg * 1216) * N_TOT + g * NV + c4 * 4;
        const float* a0p = &sAr[0][kseg * 1216];
        const float* a1p = &sAr[1][kseg * 1216];
        const float* a2p = &sAr[2][kseg * 1216];
        const float* a3p = &sAr[3][kseg * 1216];
        for (int k = 0; k < 1216; ++k) {
            float4 wv = *(const float4*)(wp + (size_t)k * N_TOT);   // shared load
            float av0 = a0p[k], av1 = a1p[k], av2 = a2p[k], av3 = a3p[k];
            ac0.x = fmaf(av0, wv.x, ac0.x); ac0.y = fmaf(av0, wv.y, ac0.y);
            ac0.z = fmaf(av0, wv.z, ac0.z); ac0.w = fmaf(av0, wv.w, ac0.w);
            ac1.x = fmaf(av1, wv.x, ac1.x); ac1.y = fmaf(av1, wv.y, ac1.y);
            ac1.z = fmaf(av1, wv.z, ac1.z); ac1.w = fmaf(av1, wv.w, ac1.w);
            ac2.x = fmaf(av2, wv.x, ac2.x); ac2.y = fmaf(av2, wv.y, ac2.y);
            ac2.z = fmaf(av2, wv.z, ac2.z); ac2.w = fmaf(av2, wv.w, ac2.w);
            ac3.x = fmaf(av3, wv.x, ac3.x); ac3.y = fmaf(av3, wv.y, ac3.y);
            ac3.z = fmaf(av3, wv.z, ac3.z); ac3.w = fmaf(av3, wv.w, ac3.w);
        }
        sPart[0][tid] = ac0; sPart[1][tid] = ac1;
        sPart[2][tid] = ac2; sPart[3][tid] = ac3;
        __syncthreads();
        if (tid < 80) {
#pragma unroll
            for (int j = 0; j < RCH_IPB; ++j) {
                float4 s = {0.f, 0.f, 0.f, 0.f};
#pragma unroll
                for (int ks = 0; ks < 4; ++ks) {          // fixed order: deterministic
                    float4 p = sPart[j][ks * 80 + tid];
                    s.x += p.x; s.y += p.y; s.z += p.z; s.w += p.w;
                }
                float4 bb = *(const float4*)(bias + g * NV + tid * 4);
                sVals[j][tid * 4 + 0] = s.x + bb.x;
                sVals[j][tid * 4 + 1] = s.y + bb.y;
                sVals[j][tid * 4 + 2] = s.z + bb.z;
                sVals[j][tid * 4 + 3] = s.w + bb.w;
            }
        }
        __syncthreads();
        if (tid < (int)nit) {
            float best = sVals[tid][0]; int bi = 0;
            for (int c = 1; c < NV; ++c)
                if (sVals[tid][c] > best) { best = sVals[tid][c]; bi = c; }  // first max wins
            packed[(size_t)sRow[tid] * GRP + g] =
                ((unsigned long long)mono_u32(best) << 32) | (unsigned int)(NV - 1 - bi);
        }
    }
}

// ---------------- gather + histogram, perplexity --------------------------------
__global__ __launch_bounds__(256)
void gather_hist(const unsigned long long* __restrict__ packed,
                 const float* __restrict__ cv,
                 float* __restrict__ out, int* __restrict__ counts)
{
    const int t = threadIdx.x;
    const int g = t >> 7;
    const int c = t & 127;
    for (int m = blockIdx.x; m < M_TOT; m += gridDim.x) {
        const unsigned long long p = packed[(size_t)m * GRP + g];
        const int idx = (NV - 1) - (int)(p & 0xFFFFFFFFull);
        out[(size_t)m * (GRP * CVD) + t] = cv[((size_t)g * NV + idx) * CVD + c];
        if (c == 0) atomicAdd(&counts[g * NV + idx], 1);
    }
}

__global__ void perplexity_k(const int* __restrict__ counts, float* __restrict__ outp)
{
    __shared__ float sred[GRP * NV];
    const int t = threadIdx.x;        // 640
    const float marg = (float)counts[t] * (1.0f / (float)M_TOT);
    sred[t] = marg * logf(marg + 1e-7f);
    __syncthreads();
    if (t < GRP) {
        float s = 0.f;
        for (int i = 0; i < NV; ++i) s += sred[t * NV + i];
        sred[t] = expf(-s);
    }
    __syncthreads();
    if (t == 0) outp[0] = sred[0] + sred[1];
}

extern "C" void kernel_launch(void* const* d_in, const int* in_sizes, int n_in,
                              void* d_out, int out_size, void* d_ws, size_t ws_size,
                              hipStream_t stream)
{
    const float* A    = (const float*)d_in[0];   // (16,1024,4864) f32
    const float* Wm   = (const float*)d_in[1];   // (4864,640) f32
    const float* bias = (const float*)d_in[2];   // (640,) f32
    const float* cv   = (const float*)d_in[3];   // (1,640,128) f32

    float* out = (float*)d_out;                       // (16,1024,256)
    float* ppl = out + (size_t)M_TOT * (GRP * CVD);   // +1 scalar

    char* ws = (char*)d_ws;
    unsigned int*       flagcnt  = (unsigned int*)(ws + WS_FLAGCNT);
    int*                counts   = (int*)(ws + WS_COUNTS);
    unsigned int*       flaglist = (unsigned int*)(ws + WS_FLAGLIST);
    unsigned long long* packed   = (unsigned long long*)(ws + WS_PACKED);
    unsigned short*     wt       = (unsigned short*)(ws + WS_WT);

    hipMemsetAsync(d_ws, 0, 4096, stream);            // flagcnt + counts
    convert_wt<<<dim3(76, 10), 256, 0, stream>>>(Wm, wt);
    gemm_mfma<<<dim3(2, 128), 512, 0, stream>>>(A, wt, bias, packed, flagcnt, flaglist);
    recheck<<<256, 320, 0, stream>>>(A, Wm, bias, flagcnt, flaglist, packed);
    gather_hist<<<4096, 256, 0, stream>>>(packed, cv, out, counts);
    perplexity_k<<<1, GRP * NV, 0, stream>>>(counts, ppl);
}

// Round 3
// 723.359 us; speedup vs baseline: 1.4402x; 1.2180x over previous
//
#include <hip/hip_runtime.h>
#include <stdint.h>

// Problem constants (fixed by the reference)
#define M_TOT 16384   // B*S
#define K_TOT 4864    // IN_DIM
#define N_TOT 640     // G*V
#define GRP   2
#define NV    320
#define CVD   128     // CV_DIM / G

// MFMA GEMM tile
#define BM 128
#define BN 320        // one full group per block (bx = group)
#define BK 32
#define KITERS (K_TOT / BK)   // 152

#define MARGIN 5.0e-4f   // approx-logit |err| measured ~3e-5 max; 8x above 2*err

typedef __attribute__((ext_vector_type(8))) short short8;
typedef __attribute__((ext_vector_type(4))) float f32x4;

// ---- ws layout (bytes) ----
#define WS_FLAGCNT  0                        // u32
#define WS_CANDCNT  4                        // u32
#define WS_COUNTS   256                      // 640 u32 (zeroed by memset w/ above)
#define WS_FLAGLIST 4096                     // 32768 u32  (cap 32768 items)
#define FLAGCAP     32768
#define WS_CANDLIST (4096 + 131072)          // 65536 u32  (cap 65536 cands)
#define CANDCAP     65536
#define WS_PACKED   (512 * 1024)             // 16384*2 u64 = 256 KB
#define WS_WT       (1u << 20)               // W_hi_t then W_lo_t, each 640*4864 u16

__device__ __forceinline__ unsigned int mono_u32(float f) {
    unsigned int b = __float_as_uint(f);
    return b ^ ((unsigned int)((int)b >> 31) | 0x80000000u);  // order-preserving
}
__device__ __forceinline__ unsigned short f2bf(float x) {   // RNE, finite inputs
    unsigned int u = __float_as_uint(x);
    return (unsigned short)((u + 0x7fffu + ((u >> 16) & 1u)) >> 16);
}
__device__ __forceinline__ float bf2f(unsigned short h) {
    return __uint_as_float(((unsigned int)h) << 16);
}
__device__ __forceinline__ void gld16(const void* g, void* l) {
    __builtin_amdgcn_global_load_lds(
        (const __attribute__((address_space(1))) unsigned int*)g,
        (__attribute__((address_space(3))) unsigned int*)l, 16, 0, 0);
}

// ---------------- W -> W_hi_t / W_lo_t (bf16, transposed to [n][k]) -------------
__global__ __launch_bounds__(256)
void convert_wt(const float* __restrict__ W, unsigned short* __restrict__ wt)
{
    __shared__ float sW[64][68];
    const int k0 = blockIdx.x * 64;          // 76 tiles
    const int n0 = blockIdx.y * 64;          // 10 tiles
    const int tid = threadIdx.x;
    for (int l = tid; l < 64 * 16; l += 256) {
        int kr = l >> 4, nc = (l & 15) * 4;
        float4 v = *(const float4*)(W + (size_t)(k0 + kr) * N_TOT + n0 + nc);
        sW[kr][nc] = v.x; sW[kr][nc + 1] = v.y; sW[kr][nc + 2] = v.z; sW[kr][nc + 3] = v.w;
    }
    __syncthreads();
    unsigned short* whi = wt;
    unsigned short* wlo = wt + (size_t)N_TOT * K_TOT;
    for (int l = tid; l < 64 * 8; l += 256) {
        int nr = l >> 3, ko = (l & 7) * 8;
        union { short8 v; unsigned short u[8]; } hu, lu;
#pragma unroll
        for (int j = 0; j < 8; ++j) {
            float x = sW[ko + j][nr];
            unsigned short hb = f2bf(x);
            hu.u[j] = hb;
            lu.u[j] = f2bf(x - bf2f(hb));
        }
        size_t off = (size_t)(n0 + nr) * K_TOT + k0 + ko;   // 16B aligned
        *(short8*)(whi + off) = hu.v;
        *(short8*)(wlo + off) = lu.v;
    }
}

// ---------------- MFMA GEMM + argmax + gather + hist + candidate flags ----------
// LDS layout: row of 64 shorts = 8 slots of 16B; slot(stream,oct,row) =
// (stream*4 + oct) ^ (row&7)  -> low bank aliasing on b128 reads (measured 5e6).
__device__ __forceinline__ void stage_b(const unsigned short* __restrict__ wt,
                                        short* sBbuf, int bx, int kk, int tid)
{
#pragma unroll
    for (int r = 0; r < 5; ++r) {
        int c = r * 512 + tid;                  // 2560 chunks = [row][slot]
        int row = c >> 3, slot = c & 7;
        int sv = slot ^ (row & 7);
        int half = sv >> 2, oct = sv & 3;       // which stream / which k-oct
        const unsigned short* gp = wt + (size_t)half * N_TOT * K_TOT
            + (size_t)(bx * NV + row) * K_TOT + kk + (oct << 3);
        gld16(gp, sBbuf + (size_t)c * 8);       // lane-linear LDS dest
    }
}

__global__ __launch_bounds__(512, 2)
void gemm_mfma(const float* __restrict__ A, const unsigned short* __restrict__ wt,
               const float* __restrict__ bias, const float* __restrict__ cv,
               float* __restrict__ out, int* __restrict__ counts,
               unsigned long long* __restrict__ packed,
               unsigned int* __restrict__ flagcnt, unsigned int* __restrict__ flaglist,
               unsigned int* __restrict__ candcnt, unsigned int* __restrict__ candlist)
{
    __shared__ short sA[2][BM][64];      // [buf][row][slot*8] 32 KB
    __shared__ short sB[2][BN][64];      // [buf][row][slot*8] 80 KB
    __shared__ uint4 sRed[BM][4];        // cross-wave argmax merge, 8 KB
    __shared__ float sThr[BM];           // flagged ? v1-MARGIN : +inf
    __shared__ unsigned sWin[BM];        // winner idx in group

    const int tid  = threadIdx.x;
    const int L    = tid & 63;
    const int w    = tid >> 6;        // 0..7
    const int quad = L >> 4;
    const int lrow = L & 15;
    const int wrow = w >> 2;          // 0..1 : rows wrow*64..
    const int wcol = w & 3;           // 0..3 : cols wcol*80..
    const int bx   = blockIdx.x;      // group 0/1
    const int m0   = blockIdx.y * BM;

    // read-side LDS slots (row&7 == lrow&7 for all frag rows)
    const int sh = (quad ^ (lrow & 7)) << 3;          // hi stream, oct=quad
    const int sl = ((4 | quad) ^ (lrow & 7)) << 3;    // lo stream, oct=quad

    // A staging mapping: thread -> (arow 0..127, aoct 0..3), 8 f32 each
    const int arow = tid >> 2;
    const int aoct = tid & 3;
    const float* Ap = A + (size_t)(m0 + arow) * K_TOT + aoct * 8;
    const int sHa = (aoct ^ (arow & 7)) << 3;
    const int sLa = ((4 | aoct) ^ (arow & 7)) << 3;

    f32x4 acc[4][5];
#pragma unroll
    for (int i = 0; i < 4; ++i)
#pragma unroll
        for (int j = 0; j < 5; ++j) acc[i][j] = (f32x4){0.f, 0.f, 0.f, 0.f};

    // ---- prologue: stage tile 0 into buf 0 (A loads issued before glds)
    {
        float4 a0 = *(const float4*)(Ap);
        float4 a1 = *(const float4*)(Ap + 4);
        stage_b(wt, &sB[0][0][0], bx, 0, tid);
        union { short8 v; unsigned short u[8]; } hu, lu;
        float xs[8] = {a0.x, a0.y, a0.z, a0.w, a1.x, a1.y, a1.z, a1.w};
#pragma unroll
        for (int j = 0; j < 8; ++j) {
            unsigned short hb = f2bf(xs[j]);
            hu.u[j] = hb; lu.u[j] = f2bf(xs[j] - bf2f(hb));
        }
        *(short8*)&sA[0][arow][sHa] = hu.v;
        *(short8*)&sA[0][arow][sLa] = lu.v;
    }
    __syncthreads();

    int k0 = 0;
    for (int it = 0; it < KITERS; ++it) {
        const int buf = it & 1;
        const int kn  = k0 + BK;
        float4 a0, a1;
        const bool more = (it + 1 < KITERS);
        if (more) {
            a0 = *(const float4*)(Ap + kn);                 // A loads FIRST (oldest
            a1 = *(const float4*)(Ap + kn + 4);             //  in vmcnt FIFO)
            stage_b(wt, &sB[buf ^ 1][0][0], bx, kn, tid);   // then async glds
        }
        // ---- MFMA on buf
        short8 ah[4], al[4];
#pragma unroll
        for (int fi = 0; fi < 4; ++fi) {
            int mloc = wrow * 64 + fi * 16 + lrow;
            ah[fi] = *(const short8*)&sA[buf][mloc][sh];
            al[fi] = *(const short8*)&sA[buf][mloc][sl];
        }
#pragma unroll
        for (int fj = 0; fj < 5; ++fj) {
            int nloc = wcol * 80 + fj * 16 + lrow;
            short8 bh = *(const short8*)&sB[buf][nloc][sh];
            short8 bl = *(const short8*)&sB[buf][nloc][sl];
#pragma unroll
            for (int fi = 0; fi < 4; ++fi) {
                acc[fi][fj] = __builtin_amdgcn_mfma_f32_16x16x32_bf16(ah[fi], bh, acc[fi][fj], 0, 0, 0);
                acc[fi][fj] = __builtin_amdgcn_mfma_f32_16x16x32_bf16(ah[fi], bl, acc[fi][fj], 0, 0, 0);
                acc[fi][fj] = __builtin_amdgcn_mfma_f32_16x16x32_bf16(al[fi], bh, acc[fi][fj], 0, 0, 0);
            }
        }
        if (more) {   // convert waits only the A loads (vmcnt leaves glds in flight)
            union { short8 v; unsigned short u[8]; } hu, lu;
            float xs[8] = {a0.x, a0.y, a0.z, a0.w, a1.x, a1.y, a1.z, a1.w};
#pragma unroll
            for (int j = 0; j < 8; ++j) {
                unsigned short hb = f2bf(xs[j]);
                hu.u[j] = hb; lu.u[j] = f2bf(xs[j] - bf2f(hb));
            }
            *(short8*)&sA[buf ^ 1][arow][sHa] = hu.v;
            *(short8*)&sA[buf ^ 1][arow][sLa] = lu.v;
        }
        __syncthreads();   // drains glds (issued ~full iter ago: cheap)
        k0 = kn;
    }

    // ---- epilogue pass 1: per-row top1(packed) + top2 value over wave's 80 cols
    float bs[5];
#pragma unroll
    for (int fj = 0; fj < 5; ++fj)
        bs[fj] = bias[bx * NV + wcol * 80 + fj * 16 + lrow];

#pragma unroll
    for (int fi = 0; fi < 4; ++fi) {
#pragma unroll
        for (int r = 0; r < 4; ++r) {
            unsigned long long pv = 0; float v1 = 0.f, v2 = -3.4e38f;
#pragma unroll
            for (int fj = 0; fj < 5; ++fj) {
                float v = acc[fi][fj][r] + bs[fj];
                int cig = wcol * 80 + fj * 16 + lrow;         // col in group
                unsigned long long p = ((unsigned long long)mono_u32(v) << 32)
                                     | (unsigned int)(NV - 1 - cig);
                if (fj == 0) { pv = p; v1 = v; }
                else if (p > pv) { v2 = v1; v1 = v; pv = p; }
                else { v2 = fmaxf(v2, v); }
            }
#pragma unroll
            for (int msk = 1; msk < 16; msk <<= 1) {          // 16 lanes share a row
                unsigned long long opv = __shfl_xor(pv, msk);
                float ov1 = __shfl_xor(v1, msk);
                float ov2 = __shfl_xor(v2, msk);
                if (opv > pv) { v2 = fmaxf(v1, ov2); v1 = ov1; pv = opv; }
                else          { v2 = fmaxf(v2, ov1); }
            }
            if (lrow == 0) {
                int row_blk = wrow * 64 + fi * 16 + quad * 4 + r;
                uint4 e;
                e.x = (unsigned int)(pv & 0xFFFFFFFFull);
                e.y = (unsigned int)(pv >> 32);
                e.z = __float_as_uint(v2);
                e.w = __float_as_uint(v1);
                sRed[row_blk][wcol] = e;
            }
        }
    }
    __syncthreads();

    if (tid < BM) {   // final 4-way merge per row: store, hist, flag, thresholds
        unsigned long long pv = 0; float v1 = -3.4e38f, v2 = -3.4e38f;
#pragma unroll
        for (int wc = 0; wc < 4; ++wc) {
            uint4 e = sRed[tid][wc];
            unsigned long long opv = ((unsigned long long)e.y << 32) | e.x;
            float ov1 = __uint_as_float(e.w), ov2 = __uint_as_float(e.z);
            if (opv > pv) { v2 = fmaxf(v1, ov2); v1 = ov1; pv = opv; }
            else          { v2 = fmaxf(v2, ov1); }
        }
        packed[(size_t)(m0 + tid) * GRP + bx] = pv;           // block-exclusive
        unsigned widx = (NV - 1) - (unsigned)(pv & 0xFFFFFFFFull);
        sWin[tid] = widx;
        atomicAdd(&counts[bx * NV + widx], 1);                // approx hist (fixed later)
        bool fl = (v1 - v2 <= MARGIN);
        sThr[tid] = fl ? (v1 - MARGIN) : 3.4e38f;
        if (fl) {
            unsigned int slot = atomicAdd(flagcnt, 1u);
            flaglist[slot] = ((unsigned int)(m0 + tid) << 1) | (unsigned int)bx;
        }
    }
    __syncthreads();

    // ---- epilogue pass 2: append candidate cols for flagged rows (rare)
#pragma unroll
    for (int fi = 0; fi < 4; ++fi) {
#pragma unroll
        for (int r = 0; r < 4; ++r) {
            int row_blk = wrow * 64 + fi * 16 + quad * 4 + r;
            float thr = sThr[row_blk];
            if (thr < 1.0e38f) {
#pragma unroll
                for (int fj = 0; fj < 5; ++fj) {
                    float v = acc[fi][fj][r] + bs[fj];        // same expr as pass 1
                    if (v >= thr) {
                        int cig = wcol * 80 + fj * 16 + lrow;
                        unsigned int slot = atomicAdd(candcnt, 1u);
                        if (slot < CANDCAP)
                            candlist[slot] = ((unsigned int)(m0 + row_blk) << 10)
                                           | ((unsigned int)bx << 9) | (unsigned int)cig;
                    }
                }
            }
        }
    }

    // ---- epilogue pass 3: gather codevectors (approx winners; recheck patches)
    {
        int row = tid >> 2, q = tid & 3;                      // 4 threads per row
        unsigned idx = sWin[row];
        const float4* cvp = (const float4*)(cv + ((size_t)bx * NV + idx) * CVD + q * 32);
        float4* op = (float4*)(out + (size_t)(m0 + row) * (GRP * CVD) + bx * CVD + q * 32);
#pragma unroll
        for (int j = 0; j < 8; ++j) op[j] = cvp[j];
    }
}

// ---------------- exact fp32 recheck: candidate columns only --------------------
// For each flagged (row,g): exact fp32 dot for each candidate column (superset
// of true argmax since MARGIN >> 2*approx_err), pick max with the same
// (value, first-index-wins) packing; patch packed/out/counts if winner changed.
__global__ __launch_bounds__(256)
void recheck(const float* __restrict__ A, const float* __restrict__ W,
             const float* __restrict__ bias, const float* __restrict__ cv,
             const unsigned int* __restrict__ flagcnt,
             const unsigned int* __restrict__ flaglist,
             const unsigned int* __restrict__ candcnt,
             const unsigned int* __restrict__ candlist,
             unsigned long long* __restrict__ packed,
             float* __restrict__ out, int* __restrict__ counts)
{
    __shared__ float sPart[256];
    __shared__ unsigned long long sBest;
    __shared__ unsigned sOld, sNew;
    const int tid = threadIdx.x;
    const unsigned fcnt = *flagcnt;
    unsigned ccnt = *candcnt; if (ccnt > CANDCAP) ccnt = CANDCAP;
    for (unsigned i = blockIdx.x; i < fcnt; i += gridDim.x) {
        unsigned item = flaglist[i];
        int m = (int)(item >> 1), g = (int)(item & 1);
        const unsigned key = item;                 // (m<<1)|g  == candlist[j]>>9
        const float* ap = A + (size_t)m * K_TOT;
        if (tid == 0) sBest = 0ull;
        __syncthreads();
        for (unsigned j = 0; j < ccnt; ++j) {      // uniform scan (cnt is tiny)
            unsigned e = candlist[j];
            if ((e >> 9) != key) continue;         // block-uniform branch
            int c = (int)(e & 511);
            // exact dot: k = tid + 256*jj, fixed per-thread fmaf chain
            const float* wp = W + (size_t)tid * N_TOT + g * NV + c;
            float part = 0.f;
#pragma unroll
            for (int jj = 0; jj < 19; ++jj)
                part = fmaf(ap[tid + 256 * jj], wp[(size_t)jj * 256 * N_TOT], part);
            sPart[tid] = part;
            __syncthreads();
            for (int s = 128; s > 0; s >>= 1) {    // fixed-order tree reduce
                if (tid < s) sPart[tid] += sPart[tid + s];
                __syncthreads();
            }
            if (tid == 0) {
                float val = sPart[0] + bias[g * NV + c];
                unsigned long long pk = ((unsigned long long)mono_u32(val) << 32)
                                      | (unsigned int)(NV - 1 - c);
                if (pk > sBest) sBest = pk;        // order-independent max
            }
            __syncthreads();
        }
        if (tid == 0) {
            unsigned long long oldp = packed[(size_t)m * GRP + g];
            sOld = (NV - 1) - (unsigned)(oldp & 0xFFFFFFFFull);
            sNew = (NV - 1) - (unsigned)(sBest & 0xFFFFFFFFull);
            if (sBest != oldp) packed[(size_t)m * GRP + g] = sBest;
            if (sNew != sOld) {
                atomicSub((unsigned int*)&counts[g * NV + sOld], 1u);
                atomicAdd(&counts[g * NV + sNew], 1);
            }
        }
        __syncthreads();
        if (sNew != sOld && tid < CVD)             // patch gathered row
            out[(size_t)m * (GRP * CVD) + g * CVD + tid] =
                cv[((size_t)g * NV + sNew) * CVD + tid];
        __syncthreads();
    }
}

// ---------------- perplexity ----------------------------------------------------
__global__ void perplexity_k(const int* __restrict__ counts, float* __restrict__ outp)
{
    __shared__ float sred[GRP * NV];
    const int t = threadIdx.x;        // 640
    const float marg = (float)counts[t] * (1.0f / (float)M_TOT);
    sred[t] = marg * logf(marg + 1e-7f);
    __syncthreads();
    if (t < GRP) {
        float s = 0.f;
        for (int i = 0; i < NV; ++i) s += sred[t * NV + i];
        sred[t] = expf(-s);
    }
    __syncthreads();
    if (t == 0) outp[0] = sred[0] + sred[1];
}

extern "C" void kernel_launch(void* const* d_in, const int* in_sizes, int n_in,
                              void* d_out, int out_size, void* d_ws, size_t ws_size,
                              hipStream_t stream)
{
    const float* A    = (const float*)d_in[0];   // (16,1024,4864) f32
    const float* Wm   = (const float*)d_in[1];   // (4864,640) f32
    const float* bias = (const float*)d_in[2];   // (640,) f32
    const float* cv   = (const float*)d_in[3];   // (1,640,128) f32

    float* out = (float*)d_out;                       // (16,1024,256)
    float* ppl = out + (size_t)M_TOT * (GRP * CVD);   // +1 scalar

    char* ws = (char*)d_ws;
    unsigned int*       flagcnt  = (unsigned int*)(ws + WS_FLAGCNT);
    unsigned int*       candcnt  = (unsigned int*)(ws + WS_CANDCNT);
    int*                counts   = (int*)(ws + WS_COUNTS);
    unsigned int*       flaglist = (unsigned int*)(ws + WS_FLAGLIST);
    unsigned int*       candlist = (unsigned int*)(ws + WS_CANDLIST);
    unsigned long long* packed   = (unsigned long long*)(ws + WS_PACKED);
    unsigned short*     wt       = (unsigned short*)(ws + WS_WT);

    hipMemsetAsync(d_ws, 0, 4096, stream);            // flagcnt + candcnt + counts
    convert_wt<<<dim3(76, 10), 256, 0, stream>>>(Wm, wt);
    gemm_mfma<<<dim3(2, 128), 512, 0, stream>>>(A, wt, bias, cv, out, counts,
                                                packed, flagcnt, flaglist,
                                                candcnt, candlist);
    recheck<<<512, 256, 0, stream>>>(A, Wm, bias, cv, flagcnt, flaglist,
                                     candcnt, candlist, packed, out, counts);
    perplexity_k<<<1, GRP * NV, 0, stream>>>(counts, ppl);
}